// Round 7
// baseline (3754.004 us; speedup 1.0000x reference)
//
#include <hip/hip_runtime.h>
#include <math.h>

// Problem constants
#define BB 4
#define TT 512
#define DIN 1536
#define HH 1024
#define THH 512
#define TFF 2048
#define NWG 256

typedef unsigned long long u64;

static __device__ __forceinline__ float4 ld4(const float* p) { return *reinterpret_cast<const float4*>(p); }

// ---------------------------------------------------------------------------
// Transpose Wp [1536][1024] -> WpT [1024][1536]
// ---------------------------------------------------------------------------
__global__ __launch_bounds__(256) void transpose_wp(const float* __restrict__ in, float* __restrict__ out) {
    __shared__ float tile[64][68];
    const int t = threadIdx.x;
    const int k0 = blockIdx.x * 64;   // over 1536
    const int n0 = blockIdx.y * 64;   // over 1024
    const int rr = t >> 4, cf = t & 15;
#pragma unroll
    for (int i = 0; i < 4; ++i) {
        const int r = rr + i * 16;
        float4 v = ld4(in + (size_t)(k0 + r) * 1024 + n0 + cf * 4);
        tile[r][cf * 4 + 0] = v.x; tile[r][cf * 4 + 1] = v.y;
        tile[r][cf * 4 + 2] = v.z; tile[r][cf * 4 + 3] = v.w;
    }
    __syncthreads();
#pragma unroll
    for (int i = 0; i < 4; ++i) {
        const int r = rr + i * 16;  // output row (n-dim)
        float4 v;
        v.x = tile[cf * 4 + 0][r]; v.y = tile[cf * 4 + 1][r];
        v.z = tile[cf * 4 + 2][r]; v.w = tile[cf * 4 + 3][r];
        *(float4*)(out + (size_t)(n0 + r) * 1536 + k0 + cf * 4) = v;
    }
}

// ---------------------------------------------------------------------------
// Transpose B_bases [2][16][4096][16] -> BT [2][16][16][4096]
// ---------------------------------------------------------------------------
__global__ __launch_bounds__(256) void transpose_b(const float* __restrict__ in, float* __restrict__ out) {
    __shared__ float tile[16][68];
    const int t = threadIdx.x;
    const int d0 = blockIdx.x * 64;
    const int n = blockIdx.y;
    const int m = blockIdx.z;
    const size_t mn = (size_t)(m * 16 + n);
    {
        const int dd = t >> 2, q = t & 3;
        float4 v = ld4(in + (mn * 4096 + d0 + dd) * 16 + q * 4);
        tile[q * 4 + 0][dd] = v.x; tile[q * 4 + 1][dd] = v.y;
        tile[q * 4 + 2][dd] = v.z; tile[q * 4 + 3][dd] = v.w;
    }
    __syncthreads();
    {
        const int r = t >> 4, df = t & 15;
        float4 v;
        v.x = tile[r][df * 4 + 0]; v.y = tile[r][df * 4 + 1];
        v.z = tile[r][df * 4 + 2]; v.w = tile[r][df * 4 + 3];
        *(float4*)(out + (mn * 16 + r) * 4096 + d0 + df * 4) = v;
    }
}

// ---------------------------------------------------------------------------
// fp32 GEMM, B given as W[N][K] (row-major, dot along rows): C = A @ W^T + bias
// BM=128 BN=128 BK=16, 256 threads, 8x8 per thread
// ---------------------------------------------------------------------------
__global__ __launch_bounds__(256) void gemm_bt(const float* __restrict__ A, const float* __restrict__ W,
                                               const float* __restrict__ bias, float* __restrict__ C,
                                               int M, int N, int K) {
    __shared__ float As[16][132];
    __shared__ float Bs[16][132];
    const int t = threadIdx.x;
    const int m0 = blockIdx.x * 128, n0 = blockIdx.y * 128;
    float acc[8][8];
#pragma unroll
    for (int i = 0; i < 8; ++i)
#pragma unroll
        for (int j = 0; j < 8; ++j) acc[i][j] = 0.f;
    const int tm = t >> 4, tn = t & 15;
    const int row = t >> 1, half = t & 1;
    for (int k0 = 0; k0 < K; k0 += 16) {
        {
            const float* asrc = A + (size_t)(m0 + row) * K + k0 + half * 8;
            float4 a0 = ld4(asrc), a1 = ld4(asrc + 4);
            const float* bsrc = W + (size_t)(n0 + row) * K + k0 + half * 8;
            float4 b0 = ld4(bsrc), b1 = ld4(bsrc + 4);
            const int kb = half * 8;
            As[kb + 0][row] = a0.x; As[kb + 1][row] = a0.y; As[kb + 2][row] = a0.z; As[kb + 3][row] = a0.w;
            As[kb + 4][row] = a1.x; As[kb + 5][row] = a1.y; As[kb + 6][row] = a1.z; As[kb + 7][row] = a1.w;
            Bs[kb + 0][row] = b0.x; Bs[kb + 1][row] = b0.y; Bs[kb + 2][row] = b0.z; Bs[kb + 3][row] = b0.w;
            Bs[kb + 4][row] = b1.x; Bs[kb + 5][row] = b1.y; Bs[kb + 6][row] = b1.z; Bs[kb + 7][row] = b1.w;
        }
        __syncthreads();
#pragma unroll
        for (int kk = 0; kk < 16; ++kk) {
            float4 a0 = *(const float4*)&As[kk][tm * 8];
            float4 a1 = *(const float4*)&As[kk][tm * 8 + 4];
            float4 b0 = *(const float4*)&Bs[kk][tn * 8];
            float4 b1 = *(const float4*)&Bs[kk][tn * 8 + 4];
            float av[8] = {a0.x, a0.y, a0.z, a0.w, a1.x, a1.y, a1.z, a1.w};
            float bv[8] = {b0.x, b0.y, b0.z, b0.w, b1.x, b1.y, b1.z, b1.w};
#pragma unroll
            for (int i = 0; i < 8; ++i)
#pragma unroll
                for (int j = 0; j < 8; ++j) acc[i][j] += av[i] * bv[j];
        }
        __syncthreads();
    }
    const int n = n0 + tn * 8;
    float4 bb0 = ld4(bias + n), bb1 = ld4(bias + n + 4);
#pragma unroll
    for (int i = 0; i < 8; ++i) {
        float4 o0, o1;
        o0.x = acc[i][0] + bb0.x; o0.y = acc[i][1] + bb0.y; o0.z = acc[i][2] + bb0.z; o0.w = acc[i][3] + bb0.w;
        o1.x = acc[i][4] + bb1.x; o1.y = acc[i][5] + bb1.y; o1.z = acc[i][6] + bb1.z; o1.w = acc[i][7] + bb1.w;
        float* dst = &C[(size_t)(m0 + tm * 8 + i) * N + n];
        *(float4*)dst = o0;
        *(float4*)(dst + 4) = o1;
    }
}

// ---------------------------------------------------------------------------
// Row LayerNorm (n == 1024), one WG per row
// ---------------------------------------------------------------------------
__global__ __launch_bounds__(256) void ln_rows(const float* __restrict__ in, float* __restrict__ out,
                                               const float* __restrict__ g, const float* __restrict__ b) {
    const int row = blockIdx.x, t = threadIdx.x;
    const float* src = in + (size_t)row * 1024;
    float v[4];
    float s = 0.f, sq = 0.f;
#pragma unroll
    for (int i = 0; i < 4; ++i) {
        float x = src[t + (i << 8)];
        v[i] = x; s += x; sq += x * x;
    }
#pragma unroll
    for (int off = 32; off; off >>= 1) { s += __shfl_xor(s, off); sq += __shfl_xor(sq, off); }
    __shared__ float rs[4], rq[4], mv[2];
    const int wv = t >> 6;
    if ((t & 63) == 0) { rs[wv] = s; rq[wv] = sq; }
    __syncthreads();
    if (t == 0) {
        float ts = rs[0] + rs[1] + rs[2] + rs[3], tq = rq[0] + rq[1] + rq[2] + rq[3];
        float mu = ts * (1.f / 1024.f);
        float var = tq * (1.f / 1024.f) - mu * mu;
        mv[0] = mu; mv[1] = rsqrtf(var + 1e-5f);
    }
    __syncthreads();
    const float mu = mv[0], rstd = mv[1];
    float* dst = out + (size_t)row * 1024;
#pragma unroll
    for (int i = 0; i < 4; ++i) {
        int idx = t + (i << 8);
        dst[idx] = (v[i] - mu) * rstd * g[idx] + b[idx];
    }
}

// ---------------------------------------------------------------------------
// Persistent-grid GRU scan, 256 WGs x 256 threads. WG w owns cols j0=4w..4w+3.
// Wave = batch b; lane = 16-element k-chunk. Whh slice held in registers.
//
// Round-4 protocol: h published as TAGGED u64 pairs (lo=f32 bits, hi=step tag)
// via relaxed agent-scope atomics (MALL-coherent, no cache maintenance).
// Consumers poll the data itself until tag matches — ONE MALL round trip per
// step (was 4: store-ack, flag store, flag poll, data load). No __syncthreads,
// no vmcnt waits: the 4 batch-groups of 256 waves free-run independently.
//
// Safety: every wave reads all 256 WGs' tagged pairs each step => inter-wave
// skew <= 1 step, so a slot (parity st&1, reused every 2 steps) is only
// overwritten after all its readers finished (their publishes are data-
// dependent on the reads). Tags are monotone (no ABA); poisoned 0xAA initial
// contents can't alias tags 1..511, so no buffer init is needed.
// ---------------------------------------------------------------------------
__global__ __launch_bounds__(256, 1) void gru_scan(const float* __restrict__ xg, const float* __restrict__ Whh,
                                                   const float* __restrict__ bhh, const int* __restrict__ lengths,
                                                   u64* __restrict__ hpub, float* __restrict__ hT) {
    const int t = threadIdx.x;
    const int b = t >> 6;
    const int lane = t & 63;
    const int w = blockIdx.x;
    const int j0 = w * 4;

    // Whh fragment in registers: rows {g*1024 + j0 + jj}, cols [lane*16, +16)
    float4 wreg[12][4];
#pragma unroll
    for (int g = 0; g < 3; ++g)
#pragma unroll
        for (int jj = 0; jj < 4; ++jj) {
            const float* src = Whh + (size_t)(g * 1024 + j0 + jj) * 1024 + lane * 16;
#pragma unroll
            for (int q = 0; q < 4; ++q) wreg[g * 4 + jj][q] = ld4(src + q * 4);
        }
    float bh0 = 0.f, bh1 = 0.f, bh2 = 0.f;
    if (lane < 4) {
        bh0 = bhh[j0 + lane];
        bh1 = bhh[1024 + j0 + lane];
        bh2 = bhh[2048 + j0 + lane];
    }
    int l0 = lengths[0], l1 = lengths[1], l2 = lengths[2], l3 = lengths[3];
    l0 = min(max(l0, 1), 512); l1 = min(max(l1, 1), 512);
    l2 = min(max(l2, 1), 512); l3 = min(max(l3, 1), 512);
    const int maxlen = max(max(l0, l1), max(l2, l3));
    const int lenb = (b == 0) ? l0 : (b == 1) ? l1 : (b == 2) ? l2 : l3;

    float hprev = 0.f;  // own h value h^st[b][j0+lane], lanes<4

    for (int st = 0; st < maxlen; ++st) {
        // issue xg loads early (independent of h)
        float xr = 0.f, xz = 0.f, xn = 0.f;
        if (lane < 4) {
            const size_t xb = ((size_t)b * 512 + st) * 3072 + j0 + lane;
            xr = xg[xb]; xz = xg[xb + 1024]; xn = xg[xb + 2048];
        }

        float hv[16];
        if (st > 0) {
            const unsigned target = (unsigned)st;
            const u64* src = hpub + (size_t)(st & 1) * 4096 + b * 1024 + lane * 16;
            u64 got[16];
#pragma unroll
            for (int i = 0; i < 16; ++i)
                got[i] = __hip_atomic_load(src + i, __ATOMIC_RELAXED, __HIP_MEMORY_SCOPE_AGENT);
            for (;;) {
                int bad = 0;
#pragma unroll
                for (int i = 0; i < 16; ++i) bad |= ((unsigned)(got[i] >> 32) != target) ? (1 << i) : 0;
                if (!bad) break;
#pragma unroll
                for (int i = 0; i < 16; ++i)
                    if (bad & (1 << i))
                        got[i] = __hip_atomic_load(src + i, __ATOMIC_RELAXED, __HIP_MEMORY_SCOPE_AGENT);
            }
#pragma unroll
            for (int i = 0; i < 16; ++i) hv[i] = __uint_as_float((unsigned)got[i]);
        } else {
#pragma unroll
            for (int q = 0; q < 16; ++q) hv[q] = 0.f;
        }

        float acc[12];
#pragma unroll
        for (int rx = 0; rx < 12; ++rx) {
            float a = 0.f;
#pragma unroll
            for (int c = 0; c < 4; ++c) {
                a += wreg[rx][c].x * hv[c * 4 + 0];
                a += wreg[rx][c].y * hv[c * 4 + 1];
                a += wreg[rx][c].z * hv[c * 4 + 2];
                a += wreg[rx][c].w * hv[c * 4 + 3];
            }
            acc[rx] = a;
        }
#pragma unroll
        for (int rx = 0; rx < 12; ++rx) {
            float a = acc[rx];
            a += __shfl_xor(a, 1);  a += __shfl_xor(a, 2);  a += __shfl_xor(a, 4);
            a += __shfl_xor(a, 8);  a += __shfl_xor(a, 16); a += __shfl_xor(a, 32);
            acc[rx] = a;
        }
        float hnew = hprev;
        if (lane < 4) {
            const float hr = acc[lane] + bh0;
            const float hz = acc[4 + lane] + bh1;
            const float hn = acc[8 + lane] + bh2;
            const float r = 1.f / (1.f + expf(-(xr + hr)));
            const float z = 1.f / (1.f + expf(-(xz + hz)));
            const float nn = tanhf(xn + r * hn);
            hnew = (st < lenb) ? ((1.f - z) * nn + z * hprev) : hprev;
        }
        hprev = hnew;

        if (st + 1 < maxlen) {
            if (lane < 4) {
                const u64 pub = ((u64)(unsigned)(st + 1) << 32) | (u64)__float_as_uint(hnew);
                __hip_atomic_store(hpub + (size_t)((st + 1) & 1) * 4096 + b * 1024 + j0 + lane, pub,
                                   __ATOMIC_RELAXED, __HIP_MEMORY_SCOPE_AGENT);
            }
        }
    }
    if (lane < 4) hT[b * 1024 + j0 + lane] = hprev;
}

// ---------------------------------------------------------------------------
// Small fused matvec: out[row][n0..n0+64) = (optLN(in_row)) @ W[K][N] + bias,
// optional exact GELU, optional residual add.
// ---------------------------------------------------------------------------
__global__ __launch_bounds__(256) void rowmv(const float* __restrict__ in, int inStride,
                                             const float* __restrict__ W, const float* __restrict__ bias,
                                             const float* __restrict__ lng, const float* __restrict__ lnb,
                                             const int doLn, const int doGelu,
                                             const float* __restrict__ resid,
                                             float* __restrict__ out, const int K, const int N) {
    __shared__ float sIn[2048];
    __shared__ float rs[4], rq[4], mv[2];
    const int t = threadIdx.x;
    const int row = blockIdx.y, n0 = blockIdx.x * 64;
    const float* src = in + (size_t)row * inStride;
    float s = 0.f, sq = 0.f;
    for (int idx = t; idx < K; idx += 256) {
        float x = src[idx];
        sIn[idx] = x; s += x; sq += x * x;
    }
    if (doLn) {
#pragma unroll
        for (int off = 32; off; off >>= 1) { s += __shfl_xor(s, off); sq += __shfl_xor(sq, off); }
        const int wv = t >> 6;
        if ((t & 63) == 0) { rs[wv] = s; rq[wv] = sq; }
        __syncthreads();
        if (t == 0) {
            float ts = rs[0] + rs[1] + rs[2] + rs[3], tq = rq[0] + rq[1] + rq[2] + rq[3];
            float mu = ts / (float)K;
            float var = tq / (float)K - mu * mu;
            mv[0] = mu; mv[1] = rsqrtf(var + 1e-5f);
        }
        __syncthreads();
        const float mu = mv[0], rstd = mv[1];
        for (int idx = t; idx < K; idx += 256) sIn[idx] = (sIn[idx] - mu) * rstd * lng[idx] + lnb[idx];
    }
    __syncthreads();
    const int n = n0 + (t >> 2), l4 = t & 3;
    const int ck = K >> 2;
    float accum = 0.f;
    const float* wcol = W + n;
    const int kbeg = l4 * ck, kend = kbeg + ck;
#pragma unroll 4
    for (int k = kbeg; k < kend; ++k) accum += sIn[k] * wcol[(size_t)k * N];
    accum += __shfl_xor(accum, 1);
    accum += __shfl_xor(accum, 2);
    if (l4 == 0) {
        accum += bias[n];
        if (doGelu) accum = accum * 0.5f * (1.f + erff(accum * 0.70710678118654752f));
        if (resid) accum += resid[(size_t)row * N + n];
        out[(size_t)row * N + n] = accum;
    }
}

// ---------------------------------------------------------------------------
// Basis combination: out[b][l][mm][r][d], mm in 0..3
//   mm<2 : sum_n coeffs[b,l,mm,n,0]   * A_bases[mm][n][r][d]
//   mm>=2: sum_n coeffs[b,l,mm-2,n,1] * BT[mm-2][n][r][d]
// ---------------------------------------------------------------------------
__global__ __launch_bounds__(256) void combine(const float* __restrict__ coeffs, const float* __restrict__ Ab,
                                               const float* __restrict__ Bt, float* __restrict__ out) {
    __shared__ float cl[128][16];
    const int t = threadIdx.x;
    const int d0 = blockIdx.x * 512;
    const int r = blockIdx.y;
    const int mm = blockIdx.z;
    const int mw = mm & 1, comp = mm >> 1;
#pragma unroll
    for (int i = 0; i < 8; ++i) {
        const int idx = t + i * 256;
        const int bl = idx >> 4, nn = idx & 15;
        const int bb = bl >> 5, ll = bl & 31;
        cl[bl][nn] = coeffs[(size_t)bb * 2048 + ((ll * 2 + mw) * 16 + nn) * 2 + comp];
    }
    __syncthreads();
    const float* bases = (mm < 2) ? Ab : Bt;
    const int d = d0 + t * 2;
    float2 bv[16];
#pragma unroll
    for (int nn = 0; nn < 16; ++nn)
        bv[nn] = *(const float2*)(bases + ((size_t)((mw * 16 + nn) * 16 + r)) * 4096 + d);
    for (int bl = 0; bl < 128; ++bl) {
        float4 c0 = *(const float4*)&cl[bl][0];
        float4 c1 = *(const float4*)&cl[bl][4];
        float4 c2 = *(const float4*)&cl[bl][8];
        float4 c3 = *(const float4*)&cl[bl][12];
        float ax, ay;
        ax = c0.x * bv[0].x + c0.y * bv[1].x + c0.z * bv[2].x + c0.w * bv[3].x
           + c1.x * bv[4].x + c1.y * bv[5].x + c1.z * bv[6].x + c1.w * bv[7].x
           + c2.x * bv[8].x + c2.y * bv[9].x + c2.z * bv[10].x + c2.w * bv[11].x
           + c3.x * bv[12].x + c3.y * bv[13].x + c3.z * bv[14].x + c3.w * bv[15].x;
        ay = c0.x * bv[0].y + c0.y * bv[1].y + c0.z * bv[2].y + c0.w * bv[3].y
           + c1.x * bv[4].y + c1.y * bv[5].y + c1.z * bv[6].y + c1.w * bv[7].y
           + c2.x * bv[8].y + c2.y * bv[9].y + c2.z * bv[10].y + c2.w * bv[11].y
           + c3.x * bv[12].y + c3.y * bv[13].y + c3.z * bv[14].y + c3.w * bv[15].y;
        *(float2*)(out + ((size_t)((bl * 4 + mm) * 16 + r)) * 4096 + d) = make_float2(ax, ay);
    }
}

// ---------------------------------------------------------------------------
// Workspace layout (float offsets)
// ---------------------------------------------------------------------------
#define R0_OFF   ((size_t)0)            // WpT (1.57M) early, BT (2.10M) late (aliased)
#define X_OFF    ((size_t)2097152)      // x  [2048][1024]
#define XG_OFF   ((size_t)4194304)      // c1 [2048][1024] aliased at front, then xg [2048][3072]
#define T0_OFF   ((size_t)10485760)
#define M1_OFF   ((size_t)10487808)
#define T1_OFF   ((size_t)10496000)
#define CO_OFF   ((size_t)10498048)
#define HP_OFF   ((size_t)10506240)     // hpub: 8192 x u64 = 16384 floats
#define HT_OFF   ((size_t)10522624)

extern "C" void kernel_launch(void* const* d_in, const int* in_sizes, int n_in,
                              void* d_out, int out_size, void* d_ws, size_t ws_size,
                              hipStream_t stream) {
    const float* fe        = (const float*)d_in[0];
    const int*   lengths   = (const int*)d_in[1];
    const float* in_proj_W = (const float*)d_in[2];
    const float* in_proj_b = (const float*)d_in[3];
    const float* in_ln_g   = (const float*)d_in[4];
    const float* in_ln_b   = (const float*)d_in[5];
    const float* gru_Wih   = (const float*)d_in[6];
    const float* gru_Whh   = (const float*)d_in[7];
    const float* gru_bih   = (const float*)d_in[8];
    const float* gru_bhh   = (const float*)d_in[9];
    const float* out_ln_g  = (const float*)d_in[10];
    const float* out_ln_b  = (const float*)d_in[11];
    const float* trunk_W   = (const float*)d_in[12];
    const float* trunk_b   = (const float*)d_in[13];
    const float* mlp_ln_g  = (const float*)d_in[14];
    const float* mlp_ln_b  = (const float*)d_in[15];
    const float* mlp_W1    = (const float*)d_in[16];
    const float* mlp_b1    = (const float*)d_in[17];
    const float* mlp_W2    = (const float*)d_in[18];
    const float* mlp_b2    = (const float*)d_in[19];
    const float* head_W    = (const float*)d_in[20];
    const float* head_b    = (const float*)d_in[21];
    const float* A_bases   = (const float*)d_in[22];
    const float* B_bases   = (const float*)d_in[23];

    float* ws = (float*)d_ws;
    float* WpT    = ws + R0_OFF;
    float* BT     = ws + R0_OFF;
    float* x      = ws + X_OFF;
    float* c1     = ws + XG_OFF;   // pre-LN proj, aliased onto xg region
    float* xg     = ws + XG_OFF;
    float* t0     = ws + T0_OFF;
    float* m1     = ws + M1_OFF;
    float* t1     = ws + T1_OFF;
    float* co     = ws + CO_OFF;
    u64*   hpub   = (u64*)(ws + HP_OFF);
    float* hT     = ws + HT_OFF;

    float* outp = (float*)d_out;

    // 1) WpT = in_proj_W^T
    transpose_wp<<<dim3(24, 16), 256, 0, stream>>>(in_proj_W, WpT);
    // 2) c1 = fe @ Wp + b            [2048,1024]
    gemm_bt<<<dim3(16, 8), 256, 0, stream>>>(fe, WpT, in_proj_b, c1, 2048, 1024, 1536);
    // 3) x = LN(c1)
    ln_rows<<<2048, 256, 0, stream>>>(c1, x, in_ln_g, in_ln_b);
    // 4) xg = x @ Wih^T + bih        [2048,3072]
    gemm_bt<<<dim3(16, 24), 256, 0, stream>>>(x, gru_Wih, gru_bih, xg, 2048, 3072, 1024);
    // 5) GRU scan -> hT [4,1024]   (tagged-pair protocol; no buffer init needed)
    gru_scan<<<NWG, 256, 0, stream>>>(xg, gru_Whh, gru_bhh, lengths, hpub, hT);
    // 6) t0 = gelu(LN_out(hT) @ trunk_W + b)
    rowmv<<<dim3(8, 4), 256, 0, stream>>>(hT, 1024, trunk_W, trunk_b, out_ln_g, out_ln_b, 1, 1, nullptr, t0, 1024, 512);
    // 7) m1 = gelu(LN_mlp(t0) @ W1 + b1)
    rowmv<<<dim3(32, 4), 256, 0, stream>>>(t0, 512, mlp_W1, mlp_b1, mlp_ln_g, mlp_ln_b, 1, 1, nullptr, m1, 512, 2048);
    // 8) t1 = t0 + m1 @ W2 + b2
    rowmv<<<dim3(8, 4), 256, 0, stream>>>(m1, 2048, mlp_W2, mlp_b2, nullptr, nullptr, 0, 0, t0, t1, 2048, 512);
    // 9) co = t1 @ head_W + head_b   [4,2048]
    rowmv<<<dim3(32, 4), 256, 0, stream>>>(t1, 512, head_W, head_b, nullptr, nullptr, 0, 0, nullptr, co, 512, 2048);
    // 10) BT = transpose(B_bases)  (reuses WpT region; WpT no longer needed)
    transpose_b<<<dim3(64, 16, 2), 256, 0, stream>>>(B_bases, BT);
    // 11) combine -> out [4,32,4,16,4096]
    combine<<<dim3(8, 16, 4), 256, 0, stream>>>(co, A_bases, BT, outp);
}

// Round 8
// 1998.495 us; speedup vs baseline: 1.8784x; 1.8784x over previous
//
#include <hip/hip_runtime.h>
#include <math.h>

// Problem constants
#define BB 4
#define TT 512
#define DIN 1536
#define HH 1024
#define THH 512
#define TFF 2048

typedef unsigned long long u64;

static __device__ __forceinline__ float4 ld4(const float* p) { return *reinterpret_cast<const float4*>(p); }

// ---------------------------------------------------------------------------
// Transpose Wp [1536][1024] -> WpT [1024][1536]
// ---------------------------------------------------------------------------
__global__ __launch_bounds__(256) void transpose_wp(const float* __restrict__ in, float* __restrict__ out) {
    __shared__ float tile[64][68];
    const int t = threadIdx.x;
    const int k0 = blockIdx.x * 64;   // over 1536
    const int n0 = blockIdx.y * 64;   // over 1024
    const int rr = t >> 4, cf = t & 15;
#pragma unroll
    for (int i = 0; i < 4; ++i) {
        const int r = rr + i * 16;
        float4 v = ld4(in + (size_t)(k0 + r) * 1024 + n0 + cf * 4);
        tile[r][cf * 4 + 0] = v.x; tile[r][cf * 4 + 1] = v.y;
        tile[r][cf * 4 + 2] = v.z; tile[r][cf * 4 + 3] = v.w;
    }
    __syncthreads();
#pragma unroll
    for (int i = 0; i < 4; ++i) {
        const int r = rr + i * 16;  // output row (n-dim)
        float4 v;
        v.x = tile[cf * 4 + 0][r]; v.y = tile[cf * 4 + 1][r];
        v.z = tile[cf * 4 + 2][r]; v.w = tile[cf * 4 + 3][r];
        *(float4*)(out + (size_t)(n0 + r) * 1536 + k0 + cf * 4) = v;
    }
}

// ---------------------------------------------------------------------------
// Transpose B_bases [2][16][4096][16] -> BT [2][16][16][4096]
// ---------------------------------------------------------------------------
__global__ __launch_bounds__(256) void transpose_b(const float* __restrict__ in, float* __restrict__ out) {
    __shared__ float tile[16][68];
    const int t = threadIdx.x;
    const int d0 = blockIdx.x * 64;
    const int n = blockIdx.y;
    const int m = blockIdx.z;
    const size_t mn = (size_t)(m * 16 + n);
    {
        const int dd = t >> 2, q = t & 3;
        float4 v = ld4(in + (mn * 4096 + d0 + dd) * 16 + q * 4);
        tile[q * 4 + 0][dd] = v.x; tile[q * 4 + 1][dd] = v.y;
        tile[q * 4 + 2][dd] = v.z; tile[q * 4 + 3][dd] = v.w;
    }
    __syncthreads();
    {
        const int r = t >> 4, df = t & 15;
        float4 v;
        v.x = tile[r][df * 4 + 0]; v.y = tile[r][df * 4 + 1];
        v.z = tile[r][df * 4 + 2]; v.w = tile[r][df * 4 + 3];
        *(float4*)(out + (mn * 16 + r) * 4096 + d0 + df * 4) = v;
    }
}

// ---------------------------------------------------------------------------
// fp32 GEMM, B given as W[N][K] (row-major, dot along rows): C = A @ W^T + bias
// BM=128 BN=128 BK=16, 256 threads, 8x8 per thread
// ---------------------------------------------------------------------------
__global__ __launch_bounds__(256) void gemm_bt(const float* __restrict__ A, const float* __restrict__ W,
                                               const float* __restrict__ bias, float* __restrict__ C,
                                               int M, int N, int K) {
    __shared__ float As[16][132];
    __shared__ float Bs[16][132];
    const int t = threadIdx.x;
    const int m0 = blockIdx.x * 128, n0 = blockIdx.y * 128;
    float acc[8][8];
#pragma unroll
    for (int i = 0; i < 8; ++i)
#pragma unroll
        for (int j = 0; j < 8; ++j) acc[i][j] = 0.f;
    const int tm = t >> 4, tn = t & 15;
    const int row = t >> 1, half = t & 1;
    for (int k0 = 0; k0 < K; k0 += 16) {
        {
            const float* asrc = A + (size_t)(m0 + row) * K + k0 + half * 8;
            float4 a0 = ld4(asrc), a1 = ld4(asrc + 4);
            const float* bsrc = W + (size_t)(n0 + row) * K + k0 + half * 8;
            float4 b0 = ld4(bsrc), b1 = ld4(bsrc + 4);
            const int kb = half * 8;
            As[kb + 0][row] = a0.x; As[kb + 1][row] = a0.y; As[kb + 2][row] = a0.z; As[kb + 3][row] = a0.w;
            As[kb + 4][row] = a1.x; As[kb + 5][row] = a1.y; As[kb + 6][row] = a1.z; As[kb + 7][row] = a1.w;
            Bs[kb + 0][row] = b0.x; Bs[kb + 1][row] = b0.y; Bs[kb + 2][row] = b0.z; Bs[kb + 3][row] = b0.w;
            Bs[kb + 4][row] = b1.x; Bs[kb + 5][row] = b1.y; Bs[kb + 6][row] = b1.z; Bs[kb + 7][row] = b1.w;
        }
        __syncthreads();
#pragma unroll
        for (int kk = 0; kk < 16; ++kk) {
            float4 a0 = *(const float4*)&As[kk][tm * 8];
            float4 a1 = *(const float4*)&As[kk][tm * 8 + 4];
            float4 b0 = *(const float4*)&Bs[kk][tn * 8];
            float4 b1 = *(const float4*)&Bs[kk][tn * 8 + 4];
            float av[8] = {a0.x, a0.y, a0.z, a0.w, a1.x, a1.y, a1.z, a1.w};
            float bv[8] = {b0.x, b0.y, b0.z, b0.w, b1.x, b1.y, b1.z, b1.w};
#pragma unroll
            for (int i = 0; i < 8; ++i)
#pragma unroll
                for (int j = 0; j < 8; ++j) acc[i][j] += av[i] * bv[j];
        }
        __syncthreads();
    }
    const int n = n0 + tn * 8;
    float4 bb0 = ld4(bias + n), bb1 = ld4(bias + n + 4);
#pragma unroll
    for (int i = 0; i < 8; ++i) {
        float4 o0, o1;
        o0.x = acc[i][0] + bb0.x; o0.y = acc[i][1] + bb0.y; o0.z = acc[i][2] + bb0.z; o0.w = acc[i][3] + bb0.w;
        o1.x = acc[i][4] + bb1.x; o1.y = acc[i][5] + bb1.y; o1.z = acc[i][6] + bb1.z; o1.w = acc[i][7] + bb1.w;
        float* dst = &C[(size_t)(m0 + tm * 8 + i) * N + n];
        *(float4*)dst = o0;
        *(float4*)(dst + 4) = o1;
    }
}

// ---------------------------------------------------------------------------
// Row LayerNorm (n == 1024), one WG per row
// ---------------------------------------------------------------------------
__global__ __launch_bounds__(256) void ln_rows(const float* __restrict__ in, float* __restrict__ out,
                                               const float* __restrict__ g, const float* __restrict__ b) {
    const int row = blockIdx.x, t = threadIdx.x;
    const float* src = in + (size_t)row * 1024;
    float v[4];
    float s = 0.f, sq = 0.f;
#pragma unroll
    for (int i = 0; i < 4; ++i) {
        float x = src[t + (i << 8)];
        v[i] = x; s += x; sq += x * x;
    }
#pragma unroll
    for (int off = 32; off; off >>= 1) { s += __shfl_xor(s, off); sq += __shfl_xor(sq, off); }
    __shared__ float rs[4], rq[4], mv[2];
    const int wv = t >> 6;
    if ((t & 63) == 0) { rs[wv] = s; rq[wv] = sq; }
    __syncthreads();
    if (t == 0) {
        float ts = rs[0] + rs[1] + rs[2] + rs[3], tq = rq[0] + rq[1] + rq[2] + rq[3];
        float mu = ts * (1.f / 1024.f);
        float var = tq * (1.f / 1024.f) - mu * mu;
        mv[0] = mu; mv[1] = rsqrtf(var + 1e-5f);
    }
    __syncthreads();
    const float mu = mv[0], rstd = mv[1];
    float* dst = out + (size_t)row * 1024;
#pragma unroll
    for (int i = 0; i < 4; ++i) {
        int idx = t + (i << 8);
        dst[idx] = (v[i] - mu) * rstd * g[idx] + b[idx];
    }
}

// ---------------------------------------------------------------------------
// GRU scan, batch-decoupled pipes. 256 WGs x 256 threads.
//   pipe b = blockIdx.x & 3 (one batch per pipe, 64 WGs each)
//   WG p (= blockIdx.x >> 2) owns output cols j0 = p*16 .. +15 of its batch.
//   Wave v handles Whh rows 12v..12v+11 (row rr = g*16+c); lane = 16-input chunk.
//
// Per-step protocol (round-3 style flags, per pipe, volume-minimized):
//   - wave 0 polls the pipe's 64 flags (s_sleep backoff); others wait at barrier.
//   - h slice (4 KB) staged ONCE into LDS via 256x16B relaxed agent atomics
//     (MALL-coherent; bypasses per-XCD L2 so no stale data).
//   - FMA from LDS + shuffle-reduce; 48 row sums assembled in LDS.
//   - gate threads (t in [64,80)) compute r/z/n, store h to the parity slot,
//     ALL threads s_waitcnt vmcnt(0) (own-store ack), barrier, t==0 publishes.
// Pipes run exactly len_b steps (no frozen-tail work, no cross-batch coupling).
// Race-freedom: flag_x >= st+1 implies WG x finished reading slot st&1, so
// writers of h^{st+2} (same slot) are safe — same induction as before.
// ---------------------------------------------------------------------------
__global__ __launch_bounds__(256, 1) void gru_scan(const float* __restrict__ xg, const float* __restrict__ Whh,
                                                   const float* __restrict__ bhh, const int* __restrict__ lengths,
                                                   float* __restrict__ hbuf, float* __restrict__ hT,
                                                   unsigned* __restrict__ flags) {
    const int t = threadIdx.x;
    const int v = t >> 6, l = t & 63;
    const int b = blockIdx.x & 3;
    const int p = blockIdx.x >> 2;
    const int j0 = p * 16;

    __shared__ float hlds[64 * 20];   // 64 chunks x 16 floats, stride 20 (16B-aligned rows, spreads banks)
    __shared__ float rowsum[48];

    // Whh fragment: wave v rows rr=12v+i (i<12), cols [l*16, +16)
    float4 wreg[12][4];
#pragma unroll
    for (int i = 0; i < 12; ++i) {
        const int rr = 12 * v + i;
        const int g = rr >> 4, c = rr & 15;
        const float* src = Whh + (size_t)(g * 1024 + j0 + c) * 1024 + l * 16;
#pragma unroll
        for (int q = 0; q < 4; ++q) wreg[i][q] = ld4(src + q * 4);
    }

    const int cg = t - 64;            // gate-thread column (valid 0..15, wave 1)
    const bool isGate = (cg >= 0) && (cg < 16);
    float bh0 = 0.f, bh1 = 0.f, bh2 = 0.f, hlast = 0.f;
    if (isGate) {
        bh0 = bhh[j0 + cg];
        bh1 = bhh[1024 + j0 + cg];
        bh2 = bhh[2048 + j0 + cg];
    }
    int lenb = lengths[b];
    lenb = min(max(lenb, 1), 512);

    unsigned* pf = flags + b * 128;          // 64 flags per pipe, 512B apart
    float* hb = hbuf + (size_t)b * 2048;     // [2][1024] per pipe

    for (int st = 0; st < lenb; ++st) {
        // xg loads (gate threads, wave 1) — issued before any barrier, overlap the poll
        float xr = 0.f, xz = 0.f, xn = 0.f;
        if (isGate) {
            const size_t xb = ((size_t)b * 512 + st) * 3072 + j0 + cg;
            xr = xg[xb]; xz = xg[xb + 1024]; xn = xg[xb + 2048];
        }
        // wave 0 polls all 64 pipe flags
        if (st > 0 && v == 0) {
            while (__hip_atomic_load(&pf[l], __ATOMIC_RELAXED, __HIP_MEMORY_SCOPE_AGENT) < (unsigned)st)
                __builtin_amdgcn_s_sleep(2);
        }
        __syncthreads();   // A: flags seen by all (or step entry at st==0)

        // stage h slot (st&1) into LDS: thread t loads 4 floats at l*16 + v*4
        float4 hstage;
        if (st > 0) {
            const u64* hs = (const u64*)(hb + (size_t)(st & 1) * 1024 + l * 16 + v * 4);
            u64 a0 = __hip_atomic_load(hs,     __ATOMIC_RELAXED, __HIP_MEMORY_SCOPE_AGENT);
            u64 a1 = __hip_atomic_load(hs + 1, __ATOMIC_RELAXED, __HIP_MEMORY_SCOPE_AGENT);
            hstage.x = __uint_as_float((unsigned)a0); hstage.y = __uint_as_float((unsigned)(a0 >> 32));
            hstage.z = __uint_as_float((unsigned)a1); hstage.w = __uint_as_float((unsigned)(a1 >> 32));
        } else {
            hstage = make_float4(0.f, 0.f, 0.f, 0.f);
        }
        *(float4*)&hlds[l * 20 + v * 4] = hstage;
        __syncthreads();   // B: h staged

        const float4 h0 = *(const float4*)&hlds[l * 20 + 0];
        const float4 h1 = *(const float4*)&hlds[l * 20 + 4];
        const float4 h2 = *(const float4*)&hlds[l * 20 + 8];
        const float4 h3 = *(const float4*)&hlds[l * 20 + 12];
        float acc[12];
#pragma unroll
        for (int i = 0; i < 12; ++i) {
            float a;
            a  = wreg[i][0].x * h0.x + wreg[i][0].y * h0.y + wreg[i][0].z * h0.z + wreg[i][0].w * h0.w;
            a += wreg[i][1].x * h1.x + wreg[i][1].y * h1.y + wreg[i][1].z * h1.z + wreg[i][1].w * h1.w;
            a += wreg[i][2].x * h2.x + wreg[i][2].y * h2.y + wreg[i][2].z * h2.z + wreg[i][2].w * h2.w;
            a += wreg[i][3].x * h3.x + wreg[i][3].y * h3.y + wreg[i][3].z * h3.z + wreg[i][3].w * h3.w;
            acc[i] = a;
        }
#pragma unroll
        for (int i = 0; i < 12; ++i) {
            float a = acc[i];
            a += __shfl_xor(a, 1);  a += __shfl_xor(a, 2);  a += __shfl_xor(a, 4);
            a += __shfl_xor(a, 8);  a += __shfl_xor(a, 16); a += __shfl_xor(a, 32);
            acc[i] = a;
        }
        if (l == 0) {
#pragma unroll
            for (int i = 0; i < 12; ++i) rowsum[12 * v + i] = acc[i];
        }
        __syncthreads();   // C: row sums ready

        if (isGate) {
            const float hr = rowsum[cg] + bh0;
            const float hz = rowsum[16 + cg] + bh1;
            const float hn = rowsum[32 + cg] + bh2;
            const float r = 1.f / (1.f + expf(-(xr + hr)));
            const float z = 1.f / (1.f + expf(-(xz + hz)));
            const float nn = tanhf(xn + r * hn);
            hlast = (1.f - z) * nn + z * hlast;
            if (st + 1 < lenb)
                __hip_atomic_store((unsigned*)&hb[(size_t)((st + 1) & 1) * 1024 + j0 + cg],
                                   __float_as_uint(hlast), __ATOMIC_RELAXED, __HIP_MEMORY_SCOPE_AGENT);
        }
        if (st + 1 < lenb) {
            asm volatile("s_waitcnt vmcnt(0)" ::: "memory");  // own h stores acked at MALL
            __syncthreads();   // D: all gate stores acked
            if (t == 0)
                __hip_atomic_store(&pf[p], (unsigned)(st + 1), __ATOMIC_RELAXED, __HIP_MEMORY_SCOPE_AGENT);
        }
    }
    if (isGate) hT[b * 1024 + j0 + cg] = hlast;
}

// ---------------------------------------------------------------------------
// Small fused matvec: out[row][n0..n0+64) = (optLN(in_row)) @ W[K][N] + bias,
// optional exact GELU, optional residual add.
// ---------------------------------------------------------------------------
__global__ __launch_bounds__(256) void rowmv(const float* __restrict__ in, int inStride,
                                             const float* __restrict__ W, const float* __restrict__ bias,
                                             const float* __restrict__ lng, const float* __restrict__ lnb,
                                             const int doLn, const int doGelu,
                                             const float* __restrict__ resid,
                                             float* __restrict__ out, const int K, const int N) {
    __shared__ float sIn[2048];
    __shared__ float rs[4], rq[4], mv[2];
    const int t = threadIdx.x;
    const int row = blockIdx.y, n0 = blockIdx.x * 64;
    const float* src = in + (size_t)row * inStride;
    float s = 0.f, sq = 0.f;
    for (int idx = t; idx < K; idx += 256) {
        float x = src[idx];
        sIn[idx] = x; s += x; sq += x * x;
    }
    if (doLn) {
#pragma unroll
        for (int off = 32; off; off >>= 1) { s += __shfl_xor(s, off); sq += __shfl_xor(sq, off); }
        const int wv = t >> 6;
        if ((t & 63) == 0) { rs[wv] = s; rq[wv] = sq; }
        __syncthreads();
        if (t == 0) {
            float ts = rs[0] + rs[1] + rs[2] + rs[3], tq = rq[0] + rq[1] + rq[2] + rq[3];
            float mu = ts / (float)K;
            float var = tq / (float)K - mu * mu;
            mv[0] = mu; mv[1] = rsqrtf(var + 1e-5f);
        }
        __syncthreads();
        const float mu = mv[0], rstd = mv[1];
        for (int idx = t; idx < K; idx += 256) sIn[idx] = (sIn[idx] - mu) * rstd * lng[idx] + lnb[idx];
    }
    __syncthreads();
    const int n = n0 + (t >> 2), l4 = t & 3;
    const int ck = K >> 2;
    float accum = 0.f;
    const float* wcol = W + n;
    const int kbeg = l4 * ck, kend = kbeg + ck;
#pragma unroll 4
    for (int k = kbeg; k < kend; ++k) accum += sIn[k] * wcol[(size_t)k * N];
    accum += __shfl_xor(accum, 1);
    accum += __shfl_xor(accum, 2);
    if (l4 == 0) {
        accum += bias[n];
        if (doGelu) accum = accum * 0.5f * (1.f + erff(accum * 0.70710678118654752f));
        if (resid) accum += resid[(size_t)row * N + n];
        out[(size_t)row * N + n] = accum;
    }
}

// ---------------------------------------------------------------------------
// Basis combination: out[b][l][mm][r][d], mm in 0..3
//   mm<2 : sum_n coeffs[b,l,mm,n,0]   * A_bases[mm][n][r][d]
//   mm>=2: sum_n coeffs[b,l,mm-2,n,1] * BT[mm-2][n][r][d]
// ---------------------------------------------------------------------------
__global__ __launch_bounds__(256) void combine(const float* __restrict__ coeffs, const float* __restrict__ Ab,
                                               const float* __restrict__ Bt, float* __restrict__ out) {
    __shared__ float cl[128][16];
    const int t = threadIdx.x;
    const int d0 = blockIdx.x * 512;
    const int r = blockIdx.y;
    const int mm = blockIdx.z;
    const int mw = mm & 1, comp = mm >> 1;
#pragma unroll
    for (int i = 0; i < 8; ++i) {
        const int idx = t + i * 256;
        const int bl = idx >> 4, nn = idx & 15;
        const int bb = bl >> 5, ll = bl & 31;
        cl[bl][nn] = coeffs[(size_t)bb * 2048 + ((ll * 2 + mw) * 16 + nn) * 2 + comp];
    }
    __syncthreads();
    const float* bases = (mm < 2) ? Ab : Bt;
    const int d = d0 + t * 2;
    float2 bv[16];
#pragma unroll
    for (int nn = 0; nn < 16; ++nn)
        bv[nn] = *(const float2*)(bases + ((size_t)((mw * 16 + nn) * 16 + r)) * 4096 + d);
    for (int bl = 0; bl < 128; ++bl) {
        float4 c0 = *(const float4*)&cl[bl][0];
        float4 c1 = *(const float4*)&cl[bl][4];
        float4 c2 = *(const float4*)&cl[bl][8];
        float4 c3 = *(const float4*)&cl[bl][12];
        float ax, ay;
        ax = c0.x * bv[0].x + c0.y * bv[1].x + c0.z * bv[2].x + c0.w * bv[3].x
           + c1.x * bv[4].x + c1.y * bv[5].x + c1.z * bv[6].x + c1.w * bv[7].x
           + c2.x * bv[8].x + c2.y * bv[9].x + c2.z * bv[10].x + c2.w * bv[11].x
           + c3.x * bv[12].x + c3.y * bv[13].x + c3.z * bv[14].x + c3.w * bv[15].x;
        ay = c0.x * bv[0].y + c0.y * bv[1].y + c0.z * bv[2].y + c0.w * bv[3].y
           + c1.x * bv[4].y + c1.y * bv[5].y + c1.z * bv[6].y + c1.w * bv[7].y
           + c2.x * bv[8].y + c2.y * bv[9].y + c2.z * bv[10].y + c2.w * bv[11].y
           + c3.x * bv[12].y + c3.y * bv[13].y + c3.z * bv[14].y + c3.w * bv[15].y;
        *(float2*)(out + ((size_t)((bl * 4 + mm) * 16 + r)) * 4096 + d) = make_float2(ax, ay);
    }
}

// ---------------------------------------------------------------------------
// Workspace layout (float offsets)
// ---------------------------------------------------------------------------
#define R0_OFF   ((size_t)0)            // WpT (1.57M) early, BT (2.10M) late (aliased)
#define X_OFF    ((size_t)2097152)      // x  [2048][1024]
#define XG_OFF   ((size_t)4194304)      // c1 [2048][1024] aliased at front, then xg [2048][3072]
#define T0_OFF   ((size_t)10485760)
#define M1_OFF   ((size_t)10487808)
#define T1_OFF   ((size_t)10496000)
#define CO_OFF   ((size_t)10498048)
#define HB_OFF   ((size_t)10506240)     // hbuf: 4 pipes x 2 slots x 1024 = 8192 floats
#define FL_OFF   ((size_t)10514432)     // flags: 4 x 128 u32 = 512 words
#define HT_OFF   ((size_t)10514944)

extern "C" void kernel_launch(void* const* d_in, const int* in_sizes, int n_in,
                              void* d_out, int out_size, void* d_ws, size_t ws_size,
                              hipStream_t stream) {
    const float* fe        = (const float*)d_in[0];
    const int*   lengths   = (const int*)d_in[1];
    const float* in_proj_W = (const float*)d_in[2];
    const float* in_proj_b = (const float*)d_in[3];
    const float* in_ln_g   = (const float*)d_in[4];
    const float* in_ln_b   = (const float*)d_in[5];
    const float* gru_Wih   = (const float*)d_in[6];
    const float* gru_Whh   = (const float*)d_in[7];
    const float* gru_bih   = (const float*)d_in[8];
    const float* gru_bhh   = (const float*)d_in[9];
    const float* out_ln_g  = (const float*)d_in[10];
    const float* out_ln_b  = (const float*)d_in[11];
    const float* trunk_W   = (const float*)d_in[12];
    const float* trunk_b   = (const float*)d_in[13];
    const float* mlp_ln_g  = (const float*)d_in[14];
    const float* mlp_ln_b  = (const float*)d_in[15];
    const float* mlp_W1    = (const float*)d_in[16];
    const float* mlp_b1    = (const float*)d_in[17];
    const float* mlp_W2    = (const float*)d_in[18];
    const float* mlp_b2    = (const float*)d_in[19];
    const float* head_W    = (const float*)d_in[20];
    const float* head_b    = (const float*)d_in[21];
    const float* A_bases   = (const float*)d_in[22];
    const float* B_bases   = (const float*)d_in[23];

    float* ws = (float*)d_ws;
    float* WpT    = ws + R0_OFF;
    float* BT     = ws + R0_OFF;
    float* x      = ws + X_OFF;
    float* c1     = ws + XG_OFF;   // pre-LN proj, aliased onto xg region
    float* xg     = ws + XG_OFF;
    float* t0     = ws + T0_OFF;
    float* m1     = ws + M1_OFF;
    float* t1     = ws + T1_OFF;
    float* co     = ws + CO_OFF;
    float* hbuf   = ws + HB_OFF;
    unsigned* flg = (unsigned*)(ws + FL_OFF);
    float* hT     = ws + HT_OFF;

    float* outp = (float*)d_out;

    // zero per-pipe publish flags (4 x 128 u32)
    hipMemsetAsync(flg, 0, 512 * sizeof(unsigned), stream);

    // 1) WpT = in_proj_W^T
    transpose_wp<<<dim3(24, 16), 256, 0, stream>>>(in_proj_W, WpT);
    // 2) c1 = fe @ Wp + b            [2048,1024]
    gemm_bt<<<dim3(16, 8), 256, 0, stream>>>(fe, WpT, in_proj_b, c1, 2048, 1024, 1536);
    // 3) x = LN(c1)
    ln_rows<<<2048, 256, 0, stream>>>(c1, x, in_ln_g, in_ln_b);
    // 4) xg = x @ Wih^T + bih        [2048,3072]
    gemm_bt<<<dim3(16, 24), 256, 0, stream>>>(x, gru_Wih, gru_bih, xg, 2048, 3072, 1024);
    // 5) GRU scan -> hT [4,1024]   (4 decoupled pipes x 64 WGs)
    gru_scan<<<256, 256, 0, stream>>>(xg, gru_Whh, gru_bhh, lengths, hbuf, hT, flg);
    // 6) t0 = gelu(LN_out(hT) @ trunk_W + b)
    rowmv<<<dim3(8, 4), 256, 0, stream>>>(hT, 1024, trunk_W, trunk_b, out_ln_g, out_ln_b, 1, 1, nullptr, t0, 1024, 512);
    // 7) m1 = gelu(LN_mlp(t0) @ W1 + b1)
    rowmv<<<dim3(32, 4), 256, 0, stream>>>(t0, 512, mlp_W1, mlp_b1, mlp_ln_g, mlp_ln_b, 1, 1, nullptr, m1, 512, 2048);
    // 8) t1 = t0 + m1 @ W2 + b2
    rowmv<<<dim3(8, 4), 256, 0, stream>>>(m1, 2048, mlp_W2, mlp_b2, nullptr, nullptr, 0, 0, t0, t1, 2048, 512);
    // 9) co = t1 @ head_W + head_b   [4,2048]
    rowmv<<<dim3(32, 4), 256, 0, stream>>>(t1, 512, head_W, head_b, nullptr, nullptr, 0, 0, nullptr, co, 512, 2048);
    // 10) BT = transpose(B_bases)  (reuses WpT region; WpT no longer needed)
    transpose_b<<<dim3(64, 16, 2), 256, 0, stream>>>(B_bases, BT);
    // 11) combine -> out [4,32,4,16,4096]
    combine<<<dim3(8, 16, 4), 256, 0, stream>>>(co, A_bases, BT, outp);
}